// Round 7
// baseline (411.593 us; speedup 1.0000x reference)
//
#include <hip/hip_runtime.h>
#include <hip/hip_bf16.h>
#include <math.h>

#define NB 1024
#define NC 100000
#define ND 512
#define SSCALE 64.0f
#define MMARGIN 0.5f

#define BM 128
#define BN 128
#define BK 64
#define NKS (ND / BK)                // 8 K-steps
#define NRT (NB / BM)                // 8 row tiles
#define NCT ((NC + BN - 1) / BN)     // 782 col tiles
#define GRIDSZ (NRT * NCT)           // 6256 = 8*782 exact -> bijective XCD swizzle

typedef __bf16 bf16x8 __attribute__((ext_vector_type(8)));
typedef float f32x4 __attribute__((ext_vector_type(4)));

__device__ __forceinline__ void gload_lds16(const void* g, void* l) {
    __builtin_amdgcn_global_load_lds(
        (const __attribute__((address_space(1))) unsigned int*)g,
        (__attribute__((address_space(3))) unsigned int*)l, 16, 0, 0);
}
__device__ __forceinline__ void bar_vm4() { asm volatile("s_waitcnt vmcnt(4)\ns_barrier" ::: "memory"); }
__device__ __forceinline__ void bar_vm8() { asm volatile("s_waitcnt vmcnt(8)\ns_barrier" ::: "memory"); }
__device__ __forceinline__ void bar_vm0() { asm volatile("s_waitcnt vmcnt(0)\ns_barrier" ::: "memory"); }

// ---------------------------------------------------------------------------
// ws layout: xnb bf16[1024][512] @0 (1MB); sums f32[1024] @1MB; tgt f32[1024];
//            Wbf bf16[100000][512] @1056768 (102.4MB) if ws_size permits.
// ---------------------------------------------------------------------------

__global__ void prep_kernel(const float* __restrict__ x, __bf16* __restrict__ xnb) {
    const int row = blockIdx.x;
    const int tid = threadIdx.x;
    const float2 v = *reinterpret_cast<const float2*>(x + (size_t)row * ND + tid * 2);
    float ss = v.x * v.x + v.y * v.y;
#pragma unroll
    for (int m = 1; m < 64; m <<= 1) ss += __shfl_xor(ss, m);
    __shared__ float wsum[4];
    if ((tid & 63) == 0) wsum[tid >> 6] = ss;
    __syncthreads();
    const float tot = wsum[0] + wsum[1] + wsum[2] + wsum[3];
    const float inv = 1.0f / fmaxf(sqrtf(tot), 1e-12f);
    __bf16* dst = xnb + (size_t)row * ND + tid * 2;
    dst[0] = (__bf16)(v.x * inv);
    dst[1] = (__bf16)(v.y * inv);
}

__global__ void target_kernel(const __bf16* __restrict__ xnb, const float* __restrict__ Wg,
                              const int* __restrict__ labels, float* __restrict__ tgt) {
    const int wid  = threadIdx.x >> 6;
    const int lane = threadIdx.x & 63;
    const int row  = blockIdx.x * 4 + wid;
    const int lab  = labels[row];
    const int k    = lane * 8;
    const bf16x8 xv = *reinterpret_cast<const bf16x8*>(xnb + (size_t)row * ND + k);
    const float* wr = Wg + (size_t)lab * ND + k;
    const float4 w0 = *reinterpret_cast<const float4*>(wr);
    const float4 w1 = *reinterpret_cast<const float4*>(wr + 4);
    float s = (float)xv[0] * w0.x + (float)xv[1] * w0.y + (float)xv[2] * w0.z + (float)xv[3] * w0.w
            + (float)xv[4] * w1.x + (float)xv[5] * w1.y + (float)xv[6] * w1.z + (float)xv[7] * w1.w;
#pragma unroll
    for (int m = 1; m < 64; m <<= 1) s += __shfl_xor(s, m);
    if (lane == 0) tgt[row] = s;
}

// W fp32 -> bf16, one shot. 25000 blocks x 256 thr, 8 elems/thread.
__global__ void cvtw_kernel(const float* __restrict__ W, __bf16* __restrict__ Wbf) {
    const size_t gid = (size_t)blockIdx.x * 256 + threadIdx.x;
    const float4 v0 = *reinterpret_cast<const float4*>(W + gid * 8);
    const float4 v1 = *reinterpret_cast<const float4*>(W + gid * 8 + 4);
    bf16x8 h;
    h[0] = (__bf16)v0.x; h[1] = (__bf16)v0.y; h[2] = (__bf16)v0.z; h[3] = (__bf16)v0.w;
    h[4] = (__bf16)v1.x; h[5] = (__bf16)v1.y; h[6] = (__bf16)v1.z; h[7] = (__bf16)v1.w;
    *reinterpret_cast<bf16x8*>(Wbf + gid * 8) = h;
}

// 128x128x64 GEMM. A: LDS dbuf (2x16KB) via gload_lds, pre-swizzled source.
// B: register-streamed MFMA fragments straight from global (bf16 Wbf if
// BMODE==0, fp32 W + in-reg cvt if BMODE==1). ONE barrier per K-step with
// counted vmcnt retiring only A's 2 gloads; B(t+2) stays in flight (T4).
// 8 waves = 2 row-groups x 4 col-groups, wave tile 64x32 (acc 4x2).
template<int BMODE>
__global__ __launch_bounds__(512, 4) void gemm_exp_kernel(const __bf16* __restrict__ xnb,
                                                          const void* __restrict__ Bsrc,
                                                          float* __restrict__ sums) {
    constexpr int NBL = (BMODE == 0) ? 4 : 8;   // B loads in flight per set
    __shared__ char lds[32768];
    const int tid  = threadIdx.x;
    const int wid  = tid >> 6;
    const int lane = tid & 63;
    const int l15  = lane & 15;
    const int lhi  = lane >> 4;
    const int wr2  = wid >> 2;       // 0..1 : 64-row group
    const int wc4  = wid & 3;        // 0..3 : 32-col group

    // bijective XCD swizzle: 6256 = 8*782
    const int logical = (blockIdx.x & 7) * (GRIDSZ / 8) + (blockIdx.x >> 3);
    const int rt = logical & 7;
    const int ct = logical >> 3;
    const int r0 = rt * BM;
    const int c0 = ct * BN;

    // per-lane B row base pointers (clamped: OOB cols masked in epilogue)
    const __bf16* bpb[2];
    const float*  bpf[2];
#pragma unroll
    for (int j = 0; j < 2; ++j) {
        int cls = c0 + wc4 * 32 + j * 16 + l15;
        cls = cls < NC ? cls : NC - 1;
        if (BMODE == 0) bpb[j] = (const __bf16*)Bsrc + (size_t)cls * ND + lhi * 8;
        else            bpf[j] = (const float*)Bsrc + (size_t)cls * ND + lhi * 8;
    }

    bf16x8 SA[2][2], SB[2][2];        // bf16 frag sets [j][kk]
    float4 RA[2][2][2], RB[2][2][2];  // fp32 staging [j][kk][half]

    auto loadB = [&](int t, bf16x8 (&S)[2][2], float4 (&R)[2][2][2]) {
#pragma unroll
        for (int j = 0; j < 2; ++j)
#pragma unroll
            for (int kk = 0; kk < 2; ++kk) {
                if constexpr (BMODE == 0) {
                    S[j][kk] = *reinterpret_cast<const bf16x8*>(bpb[j] + t * 64 + kk * 32);
                } else {
                    R[j][kk][0] = *reinterpret_cast<const float4*>(bpf[j] + t * 64 + kk * 32);
                    R[j][kk][1] = *reinterpret_cast<const float4*>(bpf[j] + t * 64 + kk * 32 + 4);
                }
            }
    };

    // A: 2 async gload_lds / thread, linear dest, pre-swizzled source (rule 21)
    auto stageA = [&](int t, int buf) {
#pragma unroll
        for (int s = 0; s < 2; ++s) {
            const int lin = s * 8192 + tid * 16;
            const int row = lin >> 7;
            const int dc  = (lin >> 4) & 7;
            const int lc  = dc ^ (row & 7);
            const char* src = (const char*)xnb + (size_t)(r0 + row) * 1024 + t * 128 + lc * 16;
            gload_lds16(src, lds + buf * 16384 + s * 8192 + wid * 1024);
        }
    };

    f32x4 acc[4][2] = {};

    auto compute = [&](int buf, bf16x8 (&S)[2][2], float4 (&R)[2][2][2]) {
#pragma unroll
        for (int kk = 0; kk < 2; ++kk) {
            bf16x8 a[4], b[2];
#pragma unroll
            for (int i = 0; i < 4; ++i) {
                const int r  = wr2 * 64 + i * 16 + l15;
                const int ck = (kk << 2) | lhi;
                a[i] = *reinterpret_cast<const bf16x8*>(
                    lds + buf * 16384 + r * 128 + ((ck ^ (r & 7)) << 4));
            }
#pragma unroll
            for (int j = 0; j < 2; ++j) {
                if constexpr (BMODE == 0) {
                    b[j] = S[j][kk];
                } else {
                    const float4 lo = R[j][kk][0], hi = R[j][kk][1];
                    bf16x8 t8;
                    t8[0] = (__bf16)lo.x; t8[1] = (__bf16)lo.y; t8[2] = (__bf16)lo.z; t8[3] = (__bf16)lo.w;
                    t8[4] = (__bf16)hi.x; t8[5] = (__bf16)hi.y; t8[6] = (__bf16)hi.z; t8[7] = (__bf16)hi.w;
                    b[j] = t8;
                }
            }
#pragma unroll
            for (int i = 0; i < 4; ++i)
#pragma unroll
                for (int j = 0; j < 2; ++j)
                    acc[i][j] = __builtin_amdgcn_mfma_f32_16x16x32_bf16(a[i], b[j], acc[i][j], 0, 0, 0);
        }
    };

    // ---- prologue: B(0), A(0), B(1); retire B(0)+A(0), keep B(1) in flight ----
    loadB(0, SA, RA);
    stageA(0, 0);
    __builtin_amdgcn_sched_barrier(0);     // pin: B(1) must queue after A(0)
    loadB(1, SB, RB);
    __builtin_amdgcn_sched_barrier(0);
    if constexpr (NBL == 4) bar_vm4(); else bar_vm8();

    // ---- main loop: fully unrolled; one counted-vmcnt barrier per step ----
#pragma unroll
    for (int tt = 0; tt < NKS; tt += 2) {
        {   const int t = tt;                         // even: consume SA
            if (t + 1 < NKS) stageA(t + 1, (t + 1) & 1);
            __builtin_amdgcn_sched_barrier(0);        // B(t+2) stays below A(t+1)
            compute(t & 1, SA, RA);
            if (t + 2 < NKS) loadB(t + 2, SA, RA);    // WAR after last SA use
            __builtin_amdgcn_sched_barrier(0);
            if (t + 1 < NKS) {
                if (t + 2 < NKS) { if constexpr (NBL == 4) bar_vm4(); else bar_vm8(); }
                else bar_vm0();
            }
        }
        {   const int t = tt + 1;                     // odd: consume SB
            if (t + 1 < NKS) stageA(t + 1, (t + 1) & 1);
            __builtin_amdgcn_sched_barrier(0);
            compute(t & 1, SB, RB);
            if (t + 2 < NKS) loadB(t + 2, SB, RB);
            __builtin_amdgcn_sched_barrier(0);
            if (t + 1 < NKS) {
                if (t + 2 < NKS) { if constexpr (NBL == 4) bar_vm4(); else bar_vm8(); }
                else bar_vm0();
            }
        }
    }

    // ---- epilogue: exp + row-sum over this wave's 32 cols + atomic ----
#pragma unroll
    for (int i = 0; i < 4; ++i) {
#pragma unroll
        for (int r = 0; r < 4; ++r) {
            float v = 0.f;
#pragma unroll
            for (int j = 0; j < 2; ++j) {
                const int c = c0 + wc4 * 32 + j * 16 + l15;
                v += (c < NC) ? __expf(SSCALE * acc[i][j][r]) : 0.f;
            }
            v += __shfl_xor(v, 1);
            v += __shfl_xor(v, 2);
            v += __shfl_xor(v, 4);
            v += __shfl_xor(v, 8);
            if (l15 == 0) {
                const int row = r0 + wr2 * 64 + i * 16 + lhi * 4 + r;
                atomicAdd(&sums[row], v);
            }
        }
    }
}

__global__ void finalize_kernel(const float* __restrict__ sums, const float* __restrict__ tgt,
                                float* __restrict__ out) {
    const int tid  = threadIdx.x;
    const int wid  = tid >> 6;
    const int lane = tid & 63;
    float t  = tgt[tid];
    const float se = sums[tid];
    t = fminf(fmaxf(t, -1.0f + 1e-7f), 1.0f - 1e-7f);
    const float numer = SSCALE * cosf(acosf(t) + MMARGIN);
    const float excl  = se - expf(SSCALE * t);
    float L = numer - logf(expf(numer) + excl);
#pragma unroll
    for (int m = 1; m < 64; m <<= 1) L += __shfl_xor(L, m);
    __shared__ float ws2[16];
    if (lane == 0) ws2[wid] = L;
    __syncthreads();
    if (tid == 0) {
        float tot = 0.f;
        for (int i = 0; i < 16; ++i) tot += ws2[i];
        out[0] = -(tot / (float)NB);
    }
}

extern "C" void kernel_launch(void* const* d_in, const int* in_sizes, int n_in,
                              void* d_out, int out_size, void* d_ws, size_t ws_size,
                              hipStream_t stream) {
    const float* x      = (const float*)d_in[0];
    const int*   labels = (const int*)d_in[1];
    const float* W      = (const float*)d_in[2];
    float* out = (float*)d_out;

    char* wsb = (char*)d_ws;
    __bf16* xnb  = (__bf16*)wsb;                       // 1MB
    float*  sums = (float*)(wsb + 1048576);            // 4KB
    float*  tgt  = (float*)(wsb + 1052672);            // 4KB
    __bf16* Wbf  = (__bf16*)(wsb + 1056768);           // 102.4MB
    const size_t WS_NEED = 1056768ull + (size_t)NC * ND * 2;

    hipMemsetAsync(sums, 0, NB * sizeof(float), stream);
    prep_kernel<<<NB, 256, 0, stream>>>(x, xnb);
    target_kernel<<<NB / 4, 256, 0, stream>>>(xnb, W, labels, tgt);
    if (ws_size >= WS_NEED) {
        cvtw_kernel<<<(NC * ND) / (256 * 8), 256, 0, stream>>>(W, Wbf);
        gemm_exp_kernel<0><<<GRIDSZ, 512, 0, stream>>>(xnb, Wbf, sums);
    } else {
        gemm_exp_kernel<1><<<GRIDSZ, 512, 0, stream>>>(xnb, W, sums);
    }
    finalize_kernel<<<1, 1024, 0, stream>>>(sums, tgt, out);
}

// Round 8
// 243.129 us; speedup vs baseline: 1.6929x; 1.6929x over previous
//
#include <hip/hip_runtime.h>
#include <hip/hip_bf16.h>
#include <math.h>

#define NB 1024
#define NC 100000
#define ND 512
#define SSCALE 64.0f
#define MMARGIN 0.5f

#define BM 256
#define BN 128
#define BK 64
#define NKS (ND / BK)                // 8 K-steps
#define NRT (NB / BM)                // 4 row tiles
#define NCT ((NC + BN - 1) / BN)     // 782 col tiles
#define GRIDSZ (NRT * NCT)           // 3128 = 8 * 391 exact -> bijective XCD swizzle
#define NCPAD 100096                 // NC padded to BN multiple (Wbf rows)

#define ABUF  32768                  // A: 2 x 32KB (256 rows x 128B)
#define BBASE 65536                  // B: single 16KB (128 cls x 128B)

typedef __bf16 bf16x8 __attribute__((ext_vector_type(8)));
typedef float f32x4 __attribute__((ext_vector_type(4)));

__device__ __forceinline__ void gload_lds16(const void* g, void* l) {
    __builtin_amdgcn_global_load_lds(
        (const __attribute__((address_space(1))) unsigned int*)g,
        (__attribute__((address_space(3))) unsigned int*)l, 16, 0, 0);
}

// ---------------------------------------------------------------------------
// ws layout: xnb bf16[1024][512] @0 (1MB); sums f32[1024] @1MB; tgt f32[1024];
//            Wbf bf16[100096][512] @1056768 (102.5MB) when ws_size permits.
// ---------------------------------------------------------------------------

__global__ void prep_kernel(const float* __restrict__ x, __bf16* __restrict__ xnb) {
    const int row = blockIdx.x;
    const int tid = threadIdx.x;
    const float2 v = *reinterpret_cast<const float2*>(x + (size_t)row * ND + tid * 2);
    float ss = v.x * v.x + v.y * v.y;
#pragma unroll
    for (int m = 1; m < 64; m <<= 1) ss += __shfl_xor(ss, m);
    __shared__ float wsum[4];
    if ((tid & 63) == 0) wsum[tid >> 6] = ss;
    __syncthreads();
    const float tot = wsum[0] + wsum[1] + wsum[2] + wsum[3];
    const float inv = 1.0f / fmaxf(sqrtf(tot), 1e-12f);
    __bf16* dst = xnb + (size_t)row * ND + tid * 2;
    dst[0] = (__bf16)(v.x * inv);
    dst[1] = (__bf16)(v.y * inv);
}

__global__ void target_kernel(const __bf16* __restrict__ xnb, const float* __restrict__ Wg,
                              const int* __restrict__ labels, float* __restrict__ tgt) {
    const int wid  = threadIdx.x >> 6;
    const int lane = threadIdx.x & 63;
    const int row  = blockIdx.x * 4 + wid;
    const int lab  = labels[row];
    const int k    = lane * 8;
    const bf16x8 xv = *reinterpret_cast<const bf16x8*>(xnb + (size_t)row * ND + k);
    const float* wr = Wg + (size_t)lab * ND + k;
    const float4 w0 = *reinterpret_cast<const float4*>(wr);
    const float4 w1 = *reinterpret_cast<const float4*>(wr + 4);
    float s = (float)xv[0] * w0.x + (float)xv[1] * w0.y + (float)xv[2] * w0.z + (float)xv[3] * w0.w
            + (float)xv[4] * w1.x + (float)xv[5] * w1.y + (float)xv[6] * w1.z + (float)xv[7] * w1.w;
#pragma unroll
    for (int m = 1; m < 64; m <<= 1) s += __shfl_xor(s, m);
    if (lane == 0) tgt[row] = s;
}

// W fp32 -> bf16 once; rows NC..NCPAD zeroed (masked in epilogue anyway).
// 25024 blocks x 256 thr x 8 elems.
__global__ void cvtw_kernel(const float* __restrict__ W, __bf16* __restrict__ Wbf) {
    const size_t gid = (size_t)blockIdx.x * 256 + threadIdx.x;
    bf16x8 h = {};
    if (gid * 8 < (size_t)NC * ND) {
        const float4 v0 = *reinterpret_cast<const float4*>(W + gid * 8);
        const float4 v1 = *reinterpret_cast<const float4*>(W + gid * 8 + 4);
        h[0] = (__bf16)v0.x; h[1] = (__bf16)v0.y; h[2] = (__bf16)v0.z; h[3] = (__bf16)v0.w;
        h[4] = (__bf16)v1.x; h[5] = (__bf16)v1.y; h[6] = (__bf16)v1.z; h[7] = (__bf16)v1.w;
    }
    *reinterpret_cast<bf16x8*>(Wbf + gid * 8) = h;
}

// 256x128x64 GEMM, R2's proven 2-barrier skeleton. A: LDS dbuf 2x32KB via
// gload_lds w16, pre-swizzled source. B: single 16KB buffer; BMODE 0 stages
// bf16 Wbf via gload_lds (2 instr/thread, no VALU); BMODE 1 falls back to
// fp32 reg-stage + cvt + swizzled ds_write. 80KB LDS -> 2 blocks/CU,
// 16 waves/CU. 8 waves = 4 row x 2 col groups, wave 64x64, 32 MFMA/interval.
// Fused exp + row-sum + atomic epilogue.
template<int BMODE>
__global__ __launch_bounds__(512, 2) void gemm_exp_kernel(const __bf16* __restrict__ xnb,
                                                          const void* __restrict__ Bsrc,
                                                          float* __restrict__ sums) {
    __shared__ char lds[81920];
    const int tid  = threadIdx.x;
    const int wid  = tid >> 6;
    const int lane = tid & 63;
    const int l15  = lane & 15;
    const int lhi  = lane >> 4;
    const int wr   = wid >> 1;       // 0..3 : 64-row group
    const int wc   = wid & 1;        // 0..1 : 64-col group

    // bijective XCD swizzle: 3128 = 8*391; consecutive logicals cycle rt
    // fastest -> 4 blocks sharing a B panel run on one XCD (L2-resident).
    const int logical = (blockIdx.x & 7) * (GRIDSZ / 8) + (blockIdx.x >> 3);
    const int rt = logical & 3;
    const int ct = logical >> 2;
    const int r0 = rt * BM;
    const int c0 = ct * BN;

    // ---- A: 4 async gload_lds / thread, linear dest, pre-swizzled source ----
    auto stageA = [&](int t, int buf) {
#pragma unroll
        for (int s = 0; s < 4; ++s) {
            const int lin = s * 8192 + wid * 1024 + lane * 16;
            const int row = lin >> 7;
            const int cnk = (lin >> 4) & 7;
            const int sc  = cnk ^ (row & 7);
            const char* src = (const char*)xnb + (size_t)(r0 + row) * 1024 + t * 128 + sc * 16;
            gload_lds16(src, lds + buf * ABUF + s * 8192 + wid * 1024);
        }
    };
    // ---- B (BMODE 0): 2 async gload_lds / thread from bf16 Wbf ----
    auto stageB = [&](int t) {
#pragma unroll
        for (int g = 0; g < 2; ++g) {
            const int lin = g * 8192 + wid * 1024 + lane * 16;
            const int cls = lin >> 7;
            const int cnk = (lin >> 4) & 7;
            const int sc  = cnk ^ (cls & 7);
            const char* src = (const char*)Bsrc + (size_t)(c0 + cls) * 1024 + t * 128 + sc * 16;
            gload_lds16(src, lds + BBASE + g * 8192 + wid * 1024);
        }
    };
    // ---- B (BMODE 1): fp32 reg-stage + cvt + swizzled ds_write ----
    const int bcls = tid >> 2;       // 0..127
    const int bq   = tid & 3;        // 16-float window
    float4 bw[4];
    auto loadB = [&](int t) {
        const float* src = (const float*)Bsrc + (size_t)(c0 + bcls) * ND + t * BK + bq * 16;
        if (c0 + bcls < NC) {
            bw[0] = *reinterpret_cast<const float4*>(src);
            bw[1] = *reinterpret_cast<const float4*>(src + 4);
            bw[2] = *reinterpret_cast<const float4*>(src + 8);
            bw[3] = *reinterpret_cast<const float4*>(src + 12);
        } else {
            bw[0] = make_float4(0.f, 0.f, 0.f, 0.f);
            bw[1] = bw[2] = bw[3] = bw[0];
        }
    };
    auto writeB = [&]() {
        struct alignas(16) bf8s { __bf16 h[8]; };
        bf8s p0, p1;
        p0.h[0] = (__bf16)bw[0].x; p0.h[1] = (__bf16)bw[0].y; p0.h[2] = (__bf16)bw[0].z; p0.h[3] = (__bf16)bw[0].w;
        p0.h[4] = (__bf16)bw[1].x; p0.h[5] = (__bf16)bw[1].y; p0.h[6] = (__bf16)bw[1].z; p0.h[7] = (__bf16)bw[1].w;
        p1.h[0] = (__bf16)bw[2].x; p1.h[1] = (__bf16)bw[2].y; p1.h[2] = (__bf16)bw[2].z; p1.h[3] = (__bf16)bw[2].w;
        p1.h[4] = (__bf16)bw[3].x; p1.h[5] = (__bf16)bw[3].y; p1.h[6] = (__bf16)bw[3].z; p1.h[7] = (__bf16)bw[3].w;
        char* base = lds + BBASE + bcls * 128;
        *reinterpret_cast<bf8s*>(base + (((bq * 2)     ^ (bcls & 7)) << 4)) = p0;
        *reinterpret_cast<bf8s*>(base + (((bq * 2 + 1) ^ (bcls & 7)) << 4)) = p1;
    };

    f32x4 acc[4][4] = {};

    auto compute = [&](int buf) {
#pragma unroll
        for (int kk = 0; kk < 2; ++kk) {
            bf16x8 a[4], b[4];
            const int ck = (kk << 2) | lhi;
#pragma unroll
            for (int i = 0; i < 4; ++i) {
                const int r = wr * 64 + i * 16 + l15;
                a[i] = *reinterpret_cast<const bf16x8*>(
                    lds + buf * ABUF + r * 128 + ((ck ^ (r & 7)) << 4));
            }
#pragma unroll
            for (int j = 0; j < 4; ++j) {
                const int cls = wc * 64 + j * 16 + l15;
                b[j] = *reinterpret_cast<const bf16x8*>(
                    lds + BBASE + cls * 128 + ((ck ^ (cls & 7)) << 4));
            }
#pragma unroll
            for (int i = 0; i < 4; ++i)
#pragma unroll
                for (int j = 0; j < 4; ++j)
                    acc[i][j] = __builtin_amdgcn_mfma_f32_16x16x32_bf16(a[i], b[j], acc[i][j], 0, 0, 0);
        }
    };

    // ---- prologue: stage A(0) + B(0); full drain ----
    stageA(0, 0);
    if constexpr (BMODE == 0) {
        stageB(0);
    } else {
        loadB(0);
        writeB();
    }
    __syncthreads();

#pragma unroll 1
    for (int t = 0; t < NKS; ++t) {
        const int buf = t & 1;
        if (t + 1 < NKS) {
            stageA(t + 1, buf ^ 1);          // issued early: hidden under compute
            if constexpr (BMODE == 1) loadB(t + 1);
        }
        compute(buf);
        if (t + 1 < NKS) {
            __syncthreads();                 // barrier 1: all B readers done
            if constexpr (BMODE == 0) stageB(t + 1);   // 2-instr issue slot
            else                      writeB();
            __syncthreads();                 // barrier 2: A(t+1)+B(t+1) landed
        }
    }

    // ---- epilogue: exp + row-sum over this wave's 64 cols + atomic ----
#pragma unroll
    for (int i = 0; i < 4; ++i) {
#pragma unroll
        for (int r = 0; r < 4; ++r) {
            float v = 0.f;
#pragma unroll
            for (int j = 0; j < 4; ++j) {
                const int c = c0 + wc * 64 + j * 16 + l15;
                v += (c < NC) ? __expf(SSCALE * acc[i][j][r]) : 0.f;
            }
            v += __shfl_xor(v, 1);
            v += __shfl_xor(v, 2);
            v += __shfl_xor(v, 4);
            v += __shfl_xor(v, 8);
            if (l15 == 0) {
                const int row = r0 + wr * 64 + i * 16 + lhi * 4 + r;
                atomicAdd(&sums[row], v);
            }
        }
    }
}

__global__ void finalize_kernel(const float* __restrict__ sums, const float* __restrict__ tgt,
                                float* __restrict__ out) {
    const int tid  = threadIdx.x;
    const int wid  = tid >> 6;
    const int lane = tid & 63;
    float t  = tgt[tid];
    const float se = sums[tid];
    t = fminf(fmaxf(t, -1.0f + 1e-7f), 1.0f - 1e-7f);
    const float numer = SSCALE * cosf(acosf(t) + MMARGIN);
    const float excl  = se - expf(SSCALE * t);
    float L = numer - logf(expf(numer) + excl);
#pragma unroll
    for (int m = 1; m < 64; m <<= 1) L += __shfl_xor(L, m);
    __shared__ float ws2[16];
    if (lane == 0) ws2[wid] = L;
    __syncthreads();
    if (tid == 0) {
        float tot = 0.f;
        for (int i = 0; i < 16; ++i) tot += ws2[i];
        out[0] = -(tot / (float)NB);
    }
}

extern "C" void kernel_launch(void* const* d_in, const int* in_sizes, int n_in,
                              void* d_out, int out_size, void* d_ws, size_t ws_size,
                              hipStream_t stream) {
    const float* x      = (const float*)d_in[0];
    const int*   labels = (const int*)d_in[1];
    const float* W      = (const float*)d_in[2];
    float* out = (float*)d_out;

    char* wsb = (char*)d_ws;
    __bf16* xnb  = (__bf16*)wsb;                       // 1MB
    float*  sums = (float*)(wsb + 1048576);            // 4KB
    float*  tgt  = (float*)(wsb + 1052672);            // 4KB
    __bf16* Wbf  = (__bf16*)(wsb + 1056768);           // 102.5MB (NCPAD rows)
    const size_t WS_NEED = 1056768ull + (size_t)NCPAD * ND * 2;

    hipMemsetAsync(sums, 0, NB * sizeof(float), stream);
    prep_kernel<<<NB, 256, 0, stream>>>(x, xnb);
    target_kernel<<<NB / 4, 256, 0, stream>>>(xnb, W, labels, tgt);
    if (ws_size >= WS_NEED) {
        cvtw_kernel<<<((size_t)NCPAD * ND) / (256 * 8), 256, 0, stream>>>(W, Wbf);
        gemm_exp_kernel<0><<<GRIDSZ, 512, 0, stream>>>(xnb, Wbf, sums);
    } else {
        gemm_exp_kernel<1><<<GRIDSZ, 512, 0, stream>>>(xnb, W, sums);
    }
    finalize_kernel<<<1, 1024, 0, stream>>>(sums, tgt, out);
}

// Round 9
// 240.571 us; speedup vs baseline: 1.7109x; 1.0106x over previous
//
#include <hip/hip_runtime.h>
#include <hip/hip_bf16.h>
#include <math.h>

#define NB 1024
#define NC 100000
#define ND 512
#define SSCALE 64.0f
#define MMARGIN 0.5f

#define BM 128
#define BN 128
#define BK 64
#define NKS (ND / BK)                // 8 K-steps
#define NRT (NB / BM)                // 8 row tiles
#define NCT ((NC + BN - 1) / BN)     // 782 col tiles
#define GRIDSZ (NRT * NCT)           // 6256 = 8*782 exact -> bijective XCD swizzle
#define NCPAD (NCT * BN)             // 100096 padded classes (Wbf rows)

#define ABUF  16384                  // A: 2 x 16KB (128 rows x 128B)
#define BBASE 32768                  // B: 2 x 16KB (128 cls x 128B)
#define BBUF  16384

typedef __bf16 bf16x8 __attribute__((ext_vector_type(8)));
typedef float f32x4 __attribute__((ext_vector_type(4)));

__device__ __forceinline__ void gload_lds16(const void* g, void* l) {
    __builtin_amdgcn_global_load_lds(
        (const __attribute__((address_space(1))) unsigned int*)g,
        (__attribute__((address_space(3))) unsigned int*)l, 16, 0, 0);
}

// ---------------------------------------------------------------------------
// ws layout: xnb bf16[1024][512] @0 (1MB); sums f32[1024] @1MB; tgt f32[1024];
//            Wbf bf16[100096][512] @1056768 (102.5MB) when ws_size permits.
// ---------------------------------------------------------------------------

__global__ void prep_kernel(const float* __restrict__ x, __bf16* __restrict__ xnb) {
    const int row = blockIdx.x;
    const int tid = threadIdx.x;
    const float2 v = *reinterpret_cast<const float2*>(x + (size_t)row * ND + tid * 2);
    float ss = v.x * v.x + v.y * v.y;
#pragma unroll
    for (int m = 1; m < 64; m <<= 1) ss += __shfl_xor(ss, m);
    __shared__ float wsum[4];
    if ((tid & 63) == 0) wsum[tid >> 6] = ss;
    __syncthreads();
    const float tot = wsum[0] + wsum[1] + wsum[2] + wsum[3];
    const float inv = 1.0f / fmaxf(sqrtf(tot), 1e-12f);
    __bf16* dst = xnb + (size_t)row * ND + tid * 2;
    dst[0] = (__bf16)(v.x * inv);
    dst[1] = (__bf16)(v.y * inv);
}

__global__ void target_kernel(const __bf16* __restrict__ xnb, const float* __restrict__ Wg,
                              const int* __restrict__ labels, float* __restrict__ tgt) {
    const int wid  = threadIdx.x >> 6;
    const int lane = threadIdx.x & 63;
    const int row  = blockIdx.x * 4 + wid;
    const int lab  = labels[row];
    const int k    = lane * 8;
    const bf16x8 xv = *reinterpret_cast<const bf16x8*>(xnb + (size_t)row * ND + k);
    const float* wr = Wg + (size_t)lab * ND + k;
    const float4 w0 = *reinterpret_cast<const float4*>(wr);
    const float4 w1 = *reinterpret_cast<const float4*>(wr + 4);
    float s = (float)xv[0] * w0.x + (float)xv[1] * w0.y + (float)xv[2] * w0.z + (float)xv[3] * w0.w
            + (float)xv[4] * w1.x + (float)xv[5] * w1.y + (float)xv[6] * w1.z + (float)xv[7] * w1.w;
#pragma unroll
    for (int m = 1; m < 64; m <<= 1) s += __shfl_xor(s, m);
    if (lane == 0) tgt[row] = s;
}

// W fp32 -> bf16 once; rows NC..NCPAD zeroed. 25024 blocks x 256 thr x 8 elems.
__global__ void cvtw_kernel(const float* __restrict__ W, __bf16* __restrict__ Wbf) {
    const size_t gid = (size_t)blockIdx.x * 256 + threadIdx.x;
    bf16x8 h = {};
    if (gid * 8 < (size_t)NC * ND) {
        const float4 v0 = *reinterpret_cast<const float4*>(W + gid * 8);
        const float4 v1 = *reinterpret_cast<const float4*>(W + gid * 8 + 4);
        h[0] = (__bf16)v0.x; h[1] = (__bf16)v0.y; h[2] = (__bf16)v0.z; h[3] = (__bf16)v0.w;
        h[4] = (__bf16)v1.x; h[5] = (__bf16)v1.y; h[6] = (__bf16)v1.z; h[7] = (__bf16)v1.w;
    }
    *reinterpret_cast<bf16x8*>(Wbf + gid * 8) = h;
}

// 128x128x64 GEMM. BOTH operands double-buffered via gload_lds w16 from bf16
// sources (A=xnb, B=Wbf), pre-swizzled source (rule 21). Stage(t+1) issued
// BEFORE compute(t) -> ~1242 cyc of cover; ONE __syncthreads per K-step; the
// vmcnt drain at the barrier is already landed. 64KB LDS -> 2 blocks/CU
// (cross-block drain cover, m114). 4 waves, wave 64x64, 32 MFMA/interval.
// BMODE 1 fallback: fp32 W reg-staged + cvt + swizzled ds_write (R2 skeleton).
template<int BMODE>
__global__ __launch_bounds__(256, 2) void gemm_exp_kernel(const __bf16* __restrict__ xnb,
                                                          const void* __restrict__ Bsrc,
                                                          float* __restrict__ sums) {
    __shared__ char lds[65536];
    const int tid  = threadIdx.x;
    const int wid  = tid >> 6;
    const int lane = tid & 63;
    const int l15  = lane & 15;
    const int lhi  = lane >> 4;
    const int wr   = wid >> 1;       // 0..1 : 64-row group
    const int wc   = wid & 1;        // 0..1 : 64-col group

    // bijective XCD swizzle: 6256 = 8*782; rt cycles fastest -> 8 blocks
    // sharing a W panel run back-to-back on one XCD (panel L2-resident).
    const int logical = (blockIdx.x & 7) * (GRIDSZ / 8) + (blockIdx.x >> 3);
    const int rt = logical & 7;
    const int ct = logical >> 3;
    const int r0 = rt * BM;
    const int c0 = ct * BN;

    // ---- A: 4 async gload_lds / thread, linear dest, pre-swizzled source ----
    auto stageA = [&](int t, int buf) {
#pragma unroll
        for (int s = 0; s < 4; ++s) {
            const int row = s * 32 + wid * 8 + (lane >> 3);
            const int lc  = (lane & 7) ^ (row & 7);
            const char* src = (const char*)xnb + (size_t)(r0 + row) * 1024 + t * 128 + lc * 16;
            gload_lds16(src, lds + buf * ABUF + s * 4096 + wid * 1024);
        }
    };
    // ---- B (BMODE 0): 4 async gload_lds / thread from bf16 Wbf ----
    auto stageB = [&](int t, int buf) {
#pragma unroll
        for (int s = 0; s < 4; ++s) {
            const int cls = s * 32 + wid * 8 + (lane >> 3);
            const int lc  = (lane & 7) ^ (cls & 7);
            const char* src = (const char*)Bsrc + (size_t)(c0 + cls) * 1024 + t * 128 + lc * 16;
            gload_lds16(src, lds + BBASE + buf * BBUF + s * 4096 + wid * 1024);
        }
    };
    // ---- B (BMODE 1): fp32 reg-stage + cvt + swizzled ds_write (R2 path) ----
    const int bcls = tid >> 3;
    const int bqp  = tid & 7;
    float4 bw[8];
    auto loadB = [&](int t) {
#pragma unroll
        for (int l = 0; l < 4; ++l) {
            const int cls = l * 32 + bcls;
            const float* src = (const float*)Bsrc + (size_t)(c0 + cls) * ND + t * BK + bqp * 8;
            if (c0 + cls < NC) {
                bw[l * 2]     = *reinterpret_cast<const float4*>(src);
                bw[l * 2 + 1] = *reinterpret_cast<const float4*>(src + 4);
            } else {
                bw[l * 2]     = make_float4(0.f, 0.f, 0.f, 0.f);
                bw[l * 2 + 1] = make_float4(0.f, 0.f, 0.f, 0.f);
            }
        }
    };
    auto writeB = [&](int buf) {
#pragma unroll
        for (int l = 0; l < 4; ++l) {
            const int cls = l * 32 + bcls;
            struct alignas(16) bf8s { __bf16 h[8]; };
            bf8s h;
            const float4 v0 = bw[l * 2], v1 = bw[l * 2 + 1];
            h.h[0] = (__bf16)v0.x; h.h[1] = (__bf16)v0.y; h.h[2] = (__bf16)v0.z; h.h[3] = (__bf16)v0.w;
            h.h[4] = (__bf16)v1.x; h.h[5] = (__bf16)v1.y; h.h[6] = (__bf16)v1.z; h.h[7] = (__bf16)v1.w;
            const int byte = BBASE + buf * BBUF + cls * 128 + ((bqp ^ (cls & 7)) << 4);
            *reinterpret_cast<bf8s*>(lds + byte) = h;
        }
    };

    f32x4 acc[4][4] = {};

    auto compute = [&](int buf) {
#pragma unroll
        for (int kk = 0; kk < 2; ++kk) {
            bf16x8 a[4], b[4];
            const int ck = (kk << 2) | lhi;
#pragma unroll
            for (int i = 0; i < 4; ++i) {
                const int r = wr * 64 + i * 16 + l15;
                a[i] = *reinterpret_cast<const bf16x8*>(
                    lds + buf * ABUF + r * 128 + ((ck ^ (r & 7)) << 4));
            }
#pragma unroll
            for (int j = 0; j < 4; ++j) {
                const int cls = wc * 64 + j * 16 + l15;
                b[j] = *reinterpret_cast<const bf16x8*>(
                    lds + BBASE + buf * BBUF + cls * 128 + ((ck ^ (cls & 7)) << 4));
            }
#pragma unroll
            for (int i = 0; i < 4; ++i)
#pragma unroll
                for (int j = 0; j < 4; ++j)
                    acc[i][j] = __builtin_amdgcn_mfma_f32_16x16x32_bf16(a[i], b[j], acc[i][j], 0, 0, 0);
        }
    };

    // ---- prologue ----
    if constexpr (BMODE == 0) {
        stageA(0, 0);
        stageB(0, 0);
        __syncthreads();
#pragma unroll 1
        for (int t = 0; t < NKS; ++t) {
            const int buf = t & 1;
            if (t + 1 < NKS) {
                stageA(t + 1, buf ^ 1);   // issued early: full compute cover
                stageB(t + 1, buf ^ 1);
            }
            compute(buf);
            __syncthreads();              // ONE barrier: drain already landed
        }
    } else {
        loadB(0);
        stageA(0, 0);
        loadB(1);   // note: reuses bw; simplified depth-1 — correctness first
        writeB(0);
        __syncthreads();
#pragma unroll 1
        for (int t = 0; t < NKS; ++t) {
            const int buf = t & 1;
            if (t + 1 < NKS) {
                stageA(t + 1, buf ^ 1);
                loadB(t + 1);
            }
            compute(buf);
            if (t + 1 < NKS) writeB(buf ^ 1);
            __syncthreads();
        }
    }

    // ---- epilogue: exp + row-sum over this wave's 64 cols + atomic ----
#pragma unroll
    for (int i = 0; i < 4; ++i) {
#pragma unroll
        for (int r = 0; r < 4; ++r) {
            float v = 0.f;
#pragma unroll
            for (int j = 0; j < 4; ++j) {
                const int c = c0 + wc * 64 + j * 16 + l15;
                v += (c < NC) ? __expf(SSCALE * acc[i][j][r]) : 0.f;
            }
            v += __shfl_xor(v, 1);
            v += __shfl_xor(v, 2);
            v += __shfl_xor(v, 4);
            v += __shfl_xor(v, 8);
            if (l15 == 0) {
                const int row = r0 + wr * 64 + i * 16 + lhi * 4 + r;
                atomicAdd(&sums[row], v);
            }
        }
    }
}

__global__ void finalize_kernel(const float* __restrict__ sums, const float* __restrict__ tgt,
                                float* __restrict__ out) {
    const int tid  = threadIdx.x;
    const int wid  = tid >> 6;
    const int lane = tid & 63;
    float t  = tgt[tid];
    const float se = sums[tid];
    t = fminf(fmaxf(t, -1.0f + 1e-7f), 1.0f - 1e-7f);
    const float numer = SSCALE * cosf(acosf(t) + MMARGIN);
    const float excl  = se - expf(SSCALE * t);
    float L = numer - logf(expf(numer) + excl);
#pragma unroll
    for (int m = 1; m < 64; m <<= 1) L += __shfl_xor(L, m);
    __shared__ float ws2[16];
    if (lane == 0) ws2[wid] = L;
    __syncthreads();
    if (tid == 0) {
        float tot = 0.f;
        for (int i = 0; i < 16; ++i) tot += ws2[i];
        out[0] = -(tot / (float)NB);
    }
}

extern "C" void kernel_launch(void* const* d_in, const int* in_sizes, int n_in,
                              void* d_out, int out_size, void* d_ws, size_t ws_size,
                              hipStream_t stream) {
    const float* x      = (const float*)d_in[0];
    const int*   labels = (const int*)d_in[1];
    const float* W      = (const float*)d_in[2];
    float* out = (float*)d_out;

    char* wsb = (char*)d_ws;
    __bf16* xnb  = (__bf16*)wsb;                       // 1MB
    float*  sums = (float*)(wsb + 1048576);            // 4KB
    float*  tgt  = (float*)(wsb + 1052672);            // 4KB
    __bf16* Wbf  = (__bf16*)(wsb + 1056768);           // 102.5MB (NCPAD rows)
    const size_t WS_NEED = 1056768ull + (size_t)NCPAD * ND * 2;

    hipMemsetAsync(sums, 0, NB * sizeof(float), stream);
    prep_kernel<<<NB, 256, 0, stream>>>(x, xnb);
    target_kernel<<<NB / 4, 256, 0, stream>>>(xnb, W, labels, tgt);
    if (ws_size >= WS_NEED) {
        cvtw_kernel<<<((size_t)NCPAD * ND) / (256 * 8), 256, 0, stream>>>(W, Wbf);
        gemm_exp_kernel<0><<<GRIDSZ, 256, 0, stream>>>(xnb, Wbf, sums);
    } else {
        gemm_exp_kernel<1><<<GRIDSZ, 256, 0, stream>>>(xnb, W, sums);
    }
    finalize_kernel<<<1, 1024, 0, stream>>>(sums, tgt, out);
}